// Round 4
// baseline (172.964 us; speedup 1.0000x reference)
//
#include <hip/hip_runtime.h>

// CARAFE on MI355X. B=4, C=256, H=W=64, CMID=64, NK=100 (s=2, k=5).
// k0a: w1 -> w1c bf16 [c8][kk][q][oc][8ic]  (exact per-chunk LDS image for k1)
// k1 : conv3x3+relu as bf16 MFMA implicit GEMM, 512 thr, async A-staging -> featb bf16 NHWC
// k2 : conv1x1 (64->100) + softmax -> kern fp32 [bh][k(25)][w(64)][s(4)] (k3-ready layout)
// k3 : ONE block per bh row; kern staged once + register-hoisted; 16 x-chunks double-buffered.
//      (Round-4 change: old k3 re-read the 25.6KB kern tile 16x per row = 410 MB of L2/L3
//       traffic, invisible to FETCH_SIZE -- that was the 55us.)
// out[b, s*64 + c/4, 2h + (c%4)/2, 2w + (c%4)%2] = sum_k kern[b,s*25+k,h,w] * xpad[b,c,h+kh-2,w+kw-2]

#define BB 4
#define CC 256
#define HH 64
#define WW 64
#define CMID 64
#define NKCH 100

typedef __bf16 bf16;
typedef __bf16 bf16x8 __attribute__((ext_vector_type(8)));
typedef float f32x4 __attribute__((ext_vector_type(4)));

__device__ __forceinline__ void async_copy16(const void* gsrc, void* ldst) {
    __builtin_amdgcn_global_load_lds(
        (__attribute__((address_space(1))) void*)(void*)gsrc,
        (__attribute__((address_space(3))) void*)ldst, 16, 0, 0);
}

// ---------------- k0a: w1 [oc][ic][3][3] fp32 -> w1c bf16 [c8][kk][q][oc][8] ----------------
__global__ void k0a_transform(const float* __restrict__ w1, bf16* __restrict__ w1c) {
    int idx = blockIdx.x * 256 + threadIdx.x;
    if (idx >= 147456) return;
    int i8 = idx & 7;
    int oc = (idx >> 3) & 63;
    int q  = (idx >> 9) & 3;
    int t2 = idx >> 11;            // 0..71
    int kk = t2 % 9;
    int c8 = t2 / 9;
    int ic = c8 * 32 + q * 8 + i8;
    w1c[idx] = (bf16)w1[(oc * 256 + ic) * 9 + kk];
}

// ---------------- k1: conv3x3 (256->64) + relu via MFMA -> featb bf16 NHWC ----------------
// grid 256 (bh), 512 threads = 8 waves. Wave (mhalf=wid&1, nq=wid>>1): 32oc x 16px tile.
__global__ __launch_bounds__(512) void k1_mfma(const float* __restrict__ x,
        const bf16* __restrict__ w1c, const float* __restrict__ b1,
        bf16* __restrict__ featb) {
    int bh = blockIdx.x;
    int b = bh >> 6, h = bh & 63;
    int tid = threadIdx.x;
    int lane = tid & 63, wid = tid >> 6;
    int l15 = lane & 15, quad = lane >> 4;
    int mhalf = wid & 1, nq = wid >> 1;

    __shared__ __align__(16) bf16 xs[3 * 66 * 40];   // [r][slot0..65][ic32+pad8]; stride 80B
    __shared__ __align__(16) bf16 wlds[36 * 512];    // [kk*4+q][oc][8ic] = chunk image

    for (int i = tid; i < 3 * 66 * 40; i += 512) xs[i] = (bf16)0.f;
    __syncthreads();

    f32x4 acc0 = {0.f, 0.f, 0.f, 0.f}, acc1 = {0.f, 0.f, 0.f, 0.f};
    const float* xb = x + (size_t)b * (CC * HH * WW);

    for (int c8 = 0; c8 < 8; ++c8) {
        // A: 36 async 1KB copies, dst = uniform base + lane*16 (contiguous image)
        for (int t = wid; t < 36; t += 8)
            async_copy16(w1c + (((c8 * 36 + t) << 9) + lane * 8), (void*)&wlds[t << 9]);
        // B: lane-coalesced fp32 row reads, packed bf16-pair ds_writes
        int ic0 = c8 * 32;
        #pragma unroll
        for (int j = 0; j < 6; ++j) {
            int task = wid + j * 8;          // 48 tasks: (p=task&15, r=task>>4)
            int p = task & 15, r = task >> 4;
            int hr = h - 1 + r;
            if (hr >= 0 && hr < HH) {
                const float* src = xb + ((size_t)(ic0 + 2 * p) * (HH * WW)) + hr * WW + lane;
                float f0 = src[0], f1 = src[HH * WW];
                union { bf16 hh[2]; unsigned u; } cv;
                cv.hh[0] = (bf16)f0; cv.hh[1] = (bf16)f1;
                *(unsigned*)&xs[(r * 66 + 1 + lane) * 40 + 2 * p] = cv.u;
            }
        }
        __syncthreads();   // drains ds_write + global_load_lds
        #pragma unroll
        for (int kk = 0; kk < 9; ++kk) {
            int r3 = kk / 3, kw = kk % 3;
            bf16x8 a0 = *(const bf16x8*)&wlds[((kk * 4 + quad) * 64 + mhalf * 32 + l15) * 8];
            bf16x8 a1 = *(const bf16x8*)&wlds[((kk * 4 + quad) * 64 + mhalf * 32 + 16 + l15) * 8];
            bf16x8 bf = *(const bf16x8*)&xs[(r3 * 66 + nq * 16 + l15 + kw) * 40 + quad * 8];
            acc0 = __builtin_amdgcn_mfma_f32_16x16x32_bf16(a0, bf, acc0, 0, 0, 0);
            acc1 = __builtin_amdgcn_mfma_f32_16x16x32_bf16(a1, bf, acc1, 0, 0, 0);
        }
        __syncthreads();
    }

    // epilogue: D col(l15)=px, row(quad*4+reg)=oc (within 16x16 tile)
    int px = nq * 16 + l15;
    #pragma unroll
    for (int mi = 0; mi < 2; ++mi) {
        int oc0 = mhalf * 32 + mi * 16 + quad * 4;
        float4 bv = *(const float4*)&b1[oc0];
        f32x4 v = mi ? acc1 : acc0;
        union { bf16 hh[4]; uint2 u; } o;
        o.hh[0] = (bf16)fmaxf(v[0] + bv.x, 0.f);
        o.hh[1] = (bf16)fmaxf(v[1] + bv.y, 0.f);
        o.hh[2] = (bf16)fmaxf(v[2] + bv.z, 0.f);
        o.hh[3] = (bf16)fmaxf(v[3] + bv.w, 0.f);
        *(uint2*)&featb[((size_t)bh * 64 + px) * 64 + oc0] = o.u;
    }
}

// ---------------- k2: conv1x1 (64->100) + softmax -> kern [bh][k][w][s] ----------------
__global__ __launch_bounds__(256) void k2_kernelpred(const bf16* __restrict__ featb,
        const float* __restrict__ w2, const float* __restrict__ b2,
        float* __restrict__ kern) {
    int bh = blockIdx.x;
    int tid = threadIdx.x;
    int w = tid & 63;
    int s = tid >> 6;                 // softmax channel = s*25 + k

    __shared__ float fs[64 * 65];
    __shared__ __align__(16) float ws2[NKCH * 64];
    __shared__ float red[2][4][64];
    __shared__ __align__(16) float kts[25 * 64 * 4];   // [k][w][s]

    for (int i = tid; i < 64 * 64; i += 256) {
        int ic = i & 63;
        int ww = i >> 6;
        fs[ic * 65 + ww] = (float)featb[(size_t)bh * 4096 + i];
    }
    for (int i = tid; i < NKCH * 64; i += 256) ws2[i] = w2[i];
    __syncthreads();

    float4 fv[16];
    #pragma unroll
    for (int q = 0; q < 16; ++q) {
        fv[q].x = fs[(4 * q + 0) * 65 + w];
        fv[q].y = fs[(4 * q + 1) * 65 + w];
        fv[q].z = fs[(4 * q + 2) * 65 + w];
        fv[q].w = fs[(4 * q + 3) * 65 + w];
    }

    float lg[25];
    for (int i = 0; i < 25; ++i) {
        int oc = s * 25 + i;
        float a = b2[oc];
        const float4* wr = (const float4*)&ws2[oc * 64];   // wave-uniform broadcast
        #pragma unroll
        for (int q = 0; q < 16; ++q) {
            float4 wv = wr[q];
            a += fv[q].x * wv.x + fv[q].y * wv.y + fv[q].z * wv.z + fv[q].w * wv.w;
        }
        lg[i] = a;
    }

    float m = -1e30f;
    #pragma unroll
    for (int i = 0; i < 25; ++i) m = fmaxf(m, lg[i]);
    red[0][s][w] = m;
    __syncthreads();
    m = fmaxf(fmaxf(red[0][0][w], red[0][1][w]), fmaxf(red[0][2][w], red[0][3][w]));
    float ssum = 0.f;
    #pragma unroll
    for (int i = 0; i < 25; ++i) { lg[i] = __expf(lg[i] - m); ssum += lg[i]; }
    red[1][s][w] = ssum;
    __syncthreads();
    ssum = red[1][0][w] + red[1][1][w] + red[1][2][w] + red[1][3][w];
    float inv = 1.f / ssum;
    #pragma unroll
    for (int i = 0; i < 25; ++i) kts[(i * 64 + w) * 4 + s] = lg[i] * inv;
    __syncthreads();
    // coalesced float4 store of the transposed block
    float* kout = kern + (size_t)bh * 6400;
    for (int i = tid; i < 1600; i += 256)
        *(float4*)&kout[i * 4] = *(const float4*)&kts[i * 4];
}

// ---------------- k3: reassembly + pixel shuffle ----------------
// grid 256 (bh), 256 thr: w=tid&63, cg=tid>>6. Block loops over 16 channel-chunks;
// kern staged ONCE (async) then hoisted to 25 f32x4 registers; x double-buffered.
__global__ __launch_bounds__(256) void k3_reassemble(const float* __restrict__ x,
        const float* __restrict__ kern, float* __restrict__ out) {
    int bh = blockIdx.x;
    int b = bh >> 6, h = bh & 63;
    int tid = threadIdx.x;
    int w = tid & 63;
    int cg = tid >> 6;                 // wave id, also channel-subgroup

    __shared__ __align__(16) float kt[6400];            // [k(25)][w(64)][s(4)]
    __shared__ __align__(16) float xs[2][5 * 68 * 20];  // [r][slot0..67][cc16+pad4]

    // kern: async memcpy 25.6 KB, once per block
    const float* ksrc = kern + (size_t)bh * 6400;
    for (int t = cg; t < 25; t += 4)
        async_copy16(ksrc + t * 256 + w * 4, (void*)&kt[t * 256]);

    // zero pad slots 0,1,66,67 of both buffers (stay zero: staging only writes slots 2..65)
    for (int i = tid; i < 640; i += 256) {
        int cc = i & 15;
        int q = (i >> 4) & 3;
        int rr = (i >> 6) % 5;
        int bufi = i / 320;
        int slot = (q < 2) ? q : (q + 64);
        xs[bufi][(rr * 68 + slot) * 20 + cc] = 0.f;
    }

    // stage chunk 0 into buf 0: thread does 5 subtasks (rr,cgrp), 4 channel loads each
    {
        const float* xc = x + ((size_t)b * CC) * (HH * WW);
        #pragma unroll
        for (int j = 0; j < 5; ++j) {
            int st = cg + j * 4;
            int rr = st >> 2, cgrp = st & 3;
            int hr = h - 2 + rr;
            float4 v = make_float4(0.f, 0.f, 0.f, 0.f);
            if (hr >= 0 && hr < HH) {
                const float* p0 = xc + ((size_t)(cgrp * 4) * (HH * WW)) + hr * WW + w;
                v.x = p0[0];
                v.y = p0[HH * WW];
                v.z = p0[2 * HH * WW];
                v.w = p0[3 * HH * WW];
            }
            *(float4*)&xs[0][(rr * 68 + 2 + w) * 20 + cgrp * 4] = v;
        }
    }
    __syncthreads();   // drains kt async + chunk-0 staging

    // hoist kern weights into registers: 25 x f32x4 (the 4 s-values for this w)
    f32x4 kv[25];
    #pragma unroll
    for (int k = 0; k < 25; ++k) kv[k] = *(const f32x4*)&kt[(k * 64 + w) * 4];

    int cg4 = cg * 4;
    for (int chunk = 0; chunk < 16; ++chunk) {
        int cur = chunk & 1;
        // stage chunk+1 into the other buffer (overlaps compute below)
        if (chunk < 15) {
            const float* xc = x + ((size_t)b * CC + (chunk + 1) * 16) * (HH * WW);
            #pragma unroll
            for (int j = 0; j < 5; ++j) {
                int st = cg + j * 4;
                int rr = st >> 2, cgrp = st & 3;
                int hr = h - 2 + rr;
                float4 v = make_float4(0.f, 0.f, 0.f, 0.f);
                if (hr >= 0 && hr < HH) {
                    const float* p0 = xc + ((size_t)(cgrp * 4) * (HH * WW)) + hr * WW + w;
                    v.x = p0[0];
                    v.y = p0[HH * WW];
                    v.z = p0[2 * HH * WW];
                    v.w = p0[3 * HH * WW];
                }
                *(float4*)&xs[cur ^ 1][(rr * 68 + 2 + w) * 20 + cgrp * 4] = v;
            }
        }
        // compute current chunk: 25 b128 LDS reads + 400 FMA per thread
        f32x4 a0 = {0.f, 0.f, 0.f, 0.f}, a1 = {0.f, 0.f, 0.f, 0.f};
        f32x4 a2 = {0.f, 0.f, 0.f, 0.f}, a3 = {0.f, 0.f, 0.f, 0.f};
        #pragma unroll
        for (int r = 0; r < 5; ++r) {
            #pragma unroll
            for (int kw = 0; kw < 5; ++kw) {
                f32x4 kvv = kv[r * 5 + kw];
                f32x4 xv = *(const f32x4*)&xs[cur][(r * 68 + w + kw) * 20 + cg4];
                a0 += kvv.x * xv;
                a1 += kvv.y * xv;
                a2 += kvv.z * xv;
                a3 += kvv.w * xv;
            }
        }
        int cq = chunk * 4 + cg;
        f32x4 accs[4] = {a0, a1, a2, a3};
        #pragma unroll
        for (int s = 0; s < 4; ++s) {
            size_t base = (((size_t)b * 256 + s * 64 + cq) * 128 + 2 * h) * 128 + 2 * w;
            *(float2*)&out[base]       = make_float2(accs[s][0], accs[s][1]);
            *(float2*)&out[base + 128] = make_float2(accs[s][2], accs[s][3]);
        }
        __syncthreads();   // protects buffer swap (next stage writes buf[cur])
    }
}

extern "C" void kernel_launch(void* const* d_in, const int* in_sizes, int n_in,
                              void* d_out, int out_size, void* d_ws, size_t ws_size,
                              hipStream_t stream) {
    const float* x  = (const float*)d_in[0];
    const float* w1 = (const float*)d_in[1];
    const float* b1 = (const float*)d_in[2];
    const float* w2 = (const float*)d_in[3];
    const float* b2 = (const float*)d_in[4];
    float* out = (float*)d_out;

    char* wsb = (char*)d_ws;
    bf16*  featb = (bf16*)wsb;                   // 2,097,152 B
    float* kern  = (float*)(wsb + 2097152);      // 6,553,600 B
    bf16*  w1c   = (bf16*)(wsb + 8650752);       // 294,912 B

    k0a_transform<<<dim3(576), 256, 0, stream>>>(w1, w1c);
    k1_mfma<<<dim3(BB * HH), 512, 0, stream>>>(x, w1c, b1, featb);
    k2_kernelpred<<<dim3(BB * HH), 256, 0, stream>>>(featb, w2, b2, kern);
    k3_reassemble<<<dim3(BB * HH), 256, 0, stream>>>(x, kern, out);
}